// Round 1
// baseline (4192.803 us; speedup 1.0000x reference)
//
#include <hip/hip_runtime.h>
#include <hip/hip_bf16.h>

// Problem constants
#define N1C   512
#define N2C   512
#define MC    1024
#define NOUTC 1024
#define WROWC 263168      // N1*N2 + N1 + N2
#define QOFFC 1024        // start of quadratic block in a W row
#define NPHASE 129        // phase 0: linear x/y; phases 1..128: 4 i-chunks each

typedef __attribute__((ext_vector_type(8))) short bf16x8;
typedef __attribute__((ext_vector_type(4))) float f32x4;

union FragU { bf16x8 v; __hip_bfloat162 h2[4]; };

__device__ __forceinline__ __hip_bfloat162 cvt2(float a, float b) {
    return __float22bfloat162_rn(make_float2(a, b));
}

// stage one 64x32 fp32 W tile -> bf16 LDS tile (row stride 40 shorts = 80B, 2-way-free banks)
__device__ __forceinline__ void stage1(short* dst, const float* wrow, int kcol, int sr, int sc8) {
    const float* src = wrow + kcol;          // wrow already includes row*WROWC + sc8
    f32x4 a = *(const f32x4*)src;
    f32x4 b = *(const f32x4*)(src + 4);
    FragU f;
    f.h2[0] = cvt2(a[0], a[1]); f.h2[1] = cvt2(a[2], a[3]);
    f.h2[2] = cvt2(b[0], b[1]); f.h2[3] = cvt2(b[2], b[3]);
    *(bf16x8*)(dst + sr * 40 + sc8) = f.v;
}

__global__ __launch_bounds__(256, 2) void quad_gemm(
        const float* __restrict__ x, const float* __restrict__ y,
        const float* __restrict__ W, float* __restrict__ out)
{
    // [buf][ii][n-row][j + pad]  : 2*4*64*40*2B = 40 KB
    __shared__ short sB[2][4][64][40];

    const int tid  = threadIdx.x;
    const int wave = tid >> 6;
    const int lane = tid & 63;
    const int quad = lane >> 4;
    const int l15  = lane & 15;

    // XCD-pair swizzle: the two m-halves of a (n-tile, j-window) slice are
    // consecutive on the same XCD (bid and bid+8) so the 2nd W read hits L2.
    const int bid   = blockIdx.x;
    const int xcd   = bid & 7;
    const int useq  = bid >> 3;                // 0..63 per XCD
    const int mh    = useq & 1;
    const int slice = (useq >> 1) + (xcd << 5); // 0..255
    const int n0 = (slice & 15) << 6;          // output-col tile base (64 wide)
    const int j0 = (slice >> 4) << 5;          // j-window base (32 wide)
    const int m0 = mh << 9;                    // batch-row half (512 rows)

    const int mbase = m0 + wave * 128 + l15;   // row of subtile s is mbase + 16*s

    // ---- y fragments: fp32, register-resident for the whole kernel ----
    float yf[8][8];
#pragma unroll
    for (int s = 0; s < 8; ++s) {
        const float* yp = y + (size_t)(mbase + s * 16) * N2C + (j0 + quad * 8);
        f32x4 a = *(const f32x4*)yp;
        f32x4 b = *(const f32x4*)(yp + 4);
#pragma unroll
        for (int t = 0; t < 4; ++t) { yf[s][t] = a[t]; yf[s][4 + t] = b[t]; }
    }

    f32x4 acc[8][4];
#pragma unroll
    for (int s = 0; s < 8; ++s)
#pragma unroll
        for (int un = 0; un < 4; ++un)
            acc[s][un] = {0.0f, 0.0f, 0.0f, 0.0f};

    // staging coordinates: thread -> (W row sr, 8-col group sc8)
    const int sr  = tid >> 2;
    const int sc8 = (tid & 3) * 8;
    const float* wrow = W + (size_t)(n0 + sr) * WROWC + sc8;

    // ---- stage phase 0: linear-x tile (ii=0) and linear-y tile (ii=1) ----
    stage1(&sB[0][0][0][0], wrow, j0,        sr, sc8);
    stage1(&sB[0][1][0][0], wrow, N1C + j0,  sr, sc8);
    __syncthreads();

    // ---- phase 0 compute: pseudo steps for the linear terms ----
    {
        bf16x8 afr[8];
        // ii = 0 : A = x[:, j-window]
#pragma unroll
        for (int s = 0; s < 8; ++s) {
            const float* xp = x + (size_t)(mbase + s * 16) * N1C + (j0 + quad * 8);
            f32x4 a = *(const f32x4*)xp;
            f32x4 b = *(const f32x4*)(xp + 4);
            FragU f;
            f.h2[0] = cvt2(a[0], a[1]); f.h2[1] = cvt2(a[2], a[3]);
            f.h2[2] = cvt2(b[0], b[1]); f.h2[3] = cvt2(b[2], b[3]);
            afr[s] = f.v;
        }
        {
            bf16x8 bfr[4];
#pragma unroll
            for (int un = 0; un < 4; ++un)
                bfr[un] = *(const bf16x8*)&sB[0][0][un * 16 + l15][quad * 8];
#pragma unroll
            for (int s = 0; s < 8; ++s)
#pragma unroll
                for (int un = 0; un < 4; ++un)
                    acc[s][un] = __builtin_amdgcn_mfma_f32_16x16x32_bf16(afr[s], bfr[un], acc[s][un], 0, 0, 0);
        }
        // ii = 1 : A = y[:, j-window]
#pragma unroll
        for (int s = 0; s < 8; ++s) {
            FragU f;
            f.h2[0] = cvt2(yf[s][0], yf[s][1]); f.h2[1] = cvt2(yf[s][2], yf[s][3]);
            f.h2[2] = cvt2(yf[s][4], yf[s][5]); f.h2[3] = cvt2(yf[s][6], yf[s][7]);
            afr[s] = f.v;
        }
        {
            bf16x8 bfr[4];
#pragma unroll
            for (int un = 0; un < 4; ++un)
                bfr[un] = *(const bf16x8*)&sB[0][1][un * 16 + l15][quad * 8];
#pragma unroll
            for (int s = 0; s < 8; ++s)
#pragma unroll
                for (int un = 0; un < 4; ++un)
                    acc[s][un] = __builtin_amdgcn_mfma_f32_16x16x32_bf16(afr[s], bfr[un], acc[s][un], 0, 0, 0);
        }
    }
    // stage phase 1 (i = 0..3) into buffer 1
    {
        const int kc0 = QOFFC + j0;
#pragma unroll
        for (int ii = 0; ii < 4; ++ii)
            stage1(&sB[1][ii][0][0], wrow, kc0 + (ii << 9), sr, sc8);
    }
    __syncthreads();

    // ---- main loop: phases 1..128, each = 4 quadratic i-steps ----
    for (int p = 1; p < NPHASE; ++p) {
        const int cur = p & 1;
        const int ibase = (p - 1) * 4;

        // x values for this phase's 4 i's (per-lane, per-subtile), L2-hot
        f32x4 xq[8];
#pragma unroll
        for (int s = 0; s < 8; ++s)
            xq[s] = *(const f32x4*)(x + (size_t)(mbase + s * 16) * N1C + ibase);

#pragma unroll
        for (int ii = 0; ii < 4; ++ii) {
            bf16x8 bfr[4];
#pragma unroll
            for (int un = 0; un < 4; ++un)
                bfr[un] = *(const bf16x8*)&sB[cur][ii][un * 16 + l15][quad * 8];
#pragma unroll
            for (int s = 0; s < 8; ++s) {
                const float xs = xq[s][ii];
                FragU f;
                f.h2[0] = cvt2(xs * yf[s][0], xs * yf[s][1]);
                f.h2[1] = cvt2(xs * yf[s][2], xs * yf[s][3]);
                f.h2[2] = cvt2(xs * yf[s][4], xs * yf[s][5]);
                f.h2[3] = cvt2(xs * yf[s][6], xs * yf[s][7]);
#pragma unroll
                for (int un = 0; un < 4; ++un)
                    acc[s][un] = __builtin_amdgcn_mfma_f32_16x16x32_bf16(f.v, bfr[un], acc[s][un], 0, 0, 0);
            }
        }

        // stage next phase's W tiles into the other buffer
        if (p + 1 < NPHASE) {
            const int nxt = cur ^ 1;
            const int kc0 = QOFFC + (p << 11) + j0;   // (p*4)*512 + j0
#pragma unroll
            for (int ii = 0; ii < 4; ++ii)
                stage1(&sB[nxt][ii][0][0], wrow, kc0 + (ii << 9), sr, sc8);
        }
        __syncthreads();
    }

    // ---- epilogue: split-K reduction via fp32 atomics ----
    // C/D layout (m89/m91): col = lane&15, row = quad*4 + reg
#pragma unroll
    for (int s = 0; s < 8; ++s) {
        const int row0 = m0 + wave * 128 + s * 16 + quad * 4;
#pragma unroll
        for (int un = 0; un < 4; ++un) {
            const int col = n0 + un * 16 + l15;
#pragma unroll
            for (int r = 0; r < 4; ++r)
                atomicAdd(out + (size_t)(row0 + r) * NOUTC + col, acc[s][un][r]);
        }
    }
}

extern "C" void kernel_launch(void* const* d_in, const int* in_sizes, int n_in,
                              void* d_out, int out_size, void* d_ws, size_t ws_size,
                              hipStream_t stream) {
    const float* x = (const float*)d_in[0];
    const float* y = (const float*)d_in[1];
    const float* W = (const float*)d_in[2];
    float* out = (float*)d_out;

    (void)hipMemsetAsync(out, 0, (size_t)out_size * sizeof(float), stream);
    quad_gemm<<<dim3(512), dim3(256), 0, stream>>>(x, y, W, out);
}